// Round 9
// baseline (224.396 us; speedup 1.0000x reference)
//
#include <hip/hip_runtime.h>
#include <hip/hip_cooperative_groups.h>

namespace cg = cooperative_groups;

#define DIM    512
#define BATCH  2048
#define NDRUG  2000
#define H1     128
#define H2     64
#define NITEM  65        // 1 pos + 64 neg per sample
#define SLAB   774144    // floats: P 2000x128 | Q 2000x128 | Qt 2048x128
#define W2F_OFF  (SLAB)               // 16 KB  W2 bf16 B-fragments
#define W1F_OFF  (W2F_OFF + 4096)     // 256 KB W1 bf16 B-fragments
#define LP       65                   // layer1 LDS pitch in short8 (+1 pad)
#define GRID     512                  // 2 blocks/CU — safely co-resident

typedef __attribute__((ext_vector_type(8))) short short8;
typedef __attribute__((ext_vector_type(4))) float floatx4;

// f32 -> bf16 RNE (bit trick; inputs finite)
__device__ inline unsigned f2bf(float x) {
    union { float f; unsigned u; } v; v.f = x;
    unsigned r = v.u + 0x7fffu + ((v.u >> 16) & 1u);
    return r >> 16;
}
__device__ inline unsigned pkbf(float a, float b) {
    return f2bf(a) | (f2bf(b) << 16);
}
__device__ inline short8 cvt8(const float* __restrict__ src) {
    float4 a = *(const float4*)src, b = *(const float4*)(src + 4);
    union { short8 s; unsigned u[4]; } v;
    v.u[0] = pkbf(a.x, a.y); v.u[1] = pkbf(a.z, a.w);
    v.u[2] = pkbf(b.x, b.y); v.u[3] = pkbf(b.z, b.w);
    return v.s;
}

// ============================ device helpers ================================
// Phase bodies shared by the fused kernel and the standalone fallbacks.

__device__ inline void pack_w_body(int blk, int tid,
    const float* __restrict__ W1, const float* __restrict__ W2,
    float* __restrict__ ws)
{
    if (blk < 64) {
        short8* W1f = (short8*)(ws + W1F_OFF);
        int item = blk * 256 + tid;                // < 16384
        int frag = item >> 6, fl = item & 63;
        int half = frag >> 7, kt = (frag >> 3) & 15, nt = frag & 7;
        int fn = fl & 15, fq = fl >> 4;
        short8 v;
        #pragma unroll
        for (int j = 0; j < 8; ++j) {
            int k = half * DIM + kt * 32 + fq * 8 + j;
            v[j] = (short)f2bf(W1[k * H1 + nt * 16 + fn]);
        }
        W1f[item] = v;
    } else if (blk == 64) {
        short8* W2f = (short8*)(ws + W2F_OFF);
        #pragma unroll
        for (int i = 0; i < 4; ++i) {
            int item = i * 256 + tid;              // < 1024
            int frag = item >> 6, fl = item & 63;
            int kt = frag >> 2, nt = frag & 3;
            int fn = fl & 15, fq = fl >> 4;
            short8 v;
            #pragma unroll
            for (int j = 0; j < 8; ++j)
                v[j] = (short)f2bf(W2[(kt * 32 + fq * 8 + j) * H2 + nt * 16 + fn]);
            W2f[item] = v;
        }
    }
}

__device__ inline void layer1_body(int blk, int tid, short8* ldsA,
    const float* __restrict__ embed, const float* __restrict__ b1,
    const int* __restrict__ t, float* __restrict__ ws)
{
    const short8* W1f = (const short8*)(ws + W1F_OFF);
    const bool isPQ = blk < 125;
    const int rowbase = isPQ ? blk * 16 : (blk - 125) * 16;
    const int lane = tid & 63, wv = tid >> 6;
    const int n = lane & 15, q = lane >> 4;

    #pragma unroll
    for (int i = 0; i < 4; ++i) {
        int u = i * 256 + tid;
        int r = u >> 6, c = u & 63;
        size_t grow = isPQ ? (size_t)(rowbase + r) : (size_t)t[rowbase + r];
        ldsA[r * LP + c] = cvt8(embed + grow * DIM + c * 8);
    }
    __syncthreads();

    if (isPQ) {
        const int T0 = wv * 4;
        const int half = (T0 >= 8) ? 1 : 0;        // 0 -> P, 1 -> Q
        floatx4 acc[4];
        #pragma unroll
        for (int i = 0; i < 4; ++i) acc[i] = (floatx4){0.f, 0.f, 0.f, 0.f};
        #pragma unroll
        for (int kt = 0; kt < 16; ++kt) {
            short8 a = ldsA[n * LP + kt * 4 + q];
            #pragma unroll
            for (int i = 0; i < 4; ++i) {
                int nt = (T0 + i) & 7;
                short8 bf = W1f[(size_t)(((half * 16 + kt) * 8) + nt) * 64 + lane];
                acc[i] = __builtin_amdgcn_mfma_f32_16x16x32_bf16(a, bf, acc[i], 0, 0, 0);
            }
        }
        float* tbl = ws + (half ? NDRUG * H1 : 0);
        #pragma unroll
        for (int i = 0; i < 4; ++i) {
            int nt = (T0 + i) & 7;
            float badd = half ? b1[nt * 16 + n] : 0.f;
            #pragma unroll
            for (int reg = 0; reg < 4; ++reg)
                tbl[(size_t)(rowbase + q * 4 + reg) * H1 + nt * 16 + n] =
                    acc[i][reg] + badd;
        }
    } else {
        const int T0 = wv * 2;                     // Qt, half 1
        floatx4 acc[2];
        #pragma unroll
        for (int i = 0; i < 2; ++i) acc[i] = (floatx4){0.f, 0.f, 0.f, 0.f};
        #pragma unroll
        for (int kt = 0; kt < 16; ++kt) {
            short8 a = ldsA[n * LP + kt * 4 + q];
            #pragma unroll
            for (int i = 0; i < 2; ++i) {
                int nt = T0 + i;
                short8 bf = W1f[(size_t)(((16 + kt) * 8) + nt) * 64 + lane];
                acc[i] = __builtin_amdgcn_mfma_f32_16x16x32_bf16(a, bf, acc[i], 0, 0, 0);
            }
        }
        float* tbl = ws + 2 * (NDRUG * H1);
        #pragma unroll
        for (int i = 0; i < 2; ++i) {
            int nt = T0 + i;
            float badd = b1[nt * 16 + n];
            #pragma unroll
            for (int reg = 0; reg < 4; ++reg)
                tbl[(size_t)(rowbase + q * 4 + reg) * H1 + nt * 16 + n] =
                    acc[i][reg] + badd;
        }
    }
}

__device__ inline void score_tile(int tile, int lane,
    const float* __restrict__ ws,
    const float* __restrict__ b2, const float* __restrict__ W3,
    const float* __restrict__ b3,
    const int* __restrict__ h, const int* __restrict__ ns,
    float* __restrict__ out)
{
    const float* P  = ws;
    const float* Q  = ws + NDRUG * H1;
    const float* Qt = Q + NDRUG * H1;
    const short8* W2f = (const short8*)(ws + W2F_OFF);
    const int n = lane & 15, q = lane >> 4;

    const int sg   = tile * 16 + n;
    const int b    = sg / NITEM;
    const int item = sg - b * NITEM;
    const float *Pr, *Qr;
    if (item == 0)       { Pr = P + h[b] * H1;                        Qr = Qt + b * H1; }
    else if (item <= 32) { Pr = P + h[b] * H1;                        Qr = Q + ns[b * 64 + item - 1] * H1; }
    else                 { Pr = P + ns[b * 64 + 32 + item - 33] * H1; Qr = Qt + b * H1; }

    floatx4 acc[4];
    #pragma unroll
    for (int nt = 0; nt < 4; ++nt) acc[nt] = (floatx4){0.f, 0.f, 0.f, 0.f};

    #pragma unroll
    for (int kt = 0; kt < 4; ++kt) {
        const int kb = kt * 32 + q * 8;
        float4 p0 = *(const float4*)(Pr + kb);
        float4 p1 = *(const float4*)(Pr + kb + 4);
        float4 q0 = *(const float4*)(Qr + kb);
        float4 q1 = *(const float4*)(Qr + kb + 4);
        union { short8 s; unsigned u[4]; } A;
        A.u[0] = pkbf(fmaxf(p0.x + q0.x, 0.f), fmaxf(p0.y + q0.y, 0.f));
        A.u[1] = pkbf(fmaxf(p0.z + q0.z, 0.f), fmaxf(p0.w + q0.w, 0.f));
        A.u[2] = pkbf(fmaxf(p1.x + q1.x, 0.f), fmaxf(p1.y + q1.y, 0.f));
        A.u[3] = pkbf(fmaxf(p1.z + q1.z, 0.f), fmaxf(p1.w + q1.w, 0.f));
        #pragma unroll
        for (int nt = 0; nt < 4; ++nt) {
            short8 bf = W2f[(kt * 4 + nt) * 64 + lane];
            acc[nt] = __builtin_amdgcn_mfma_f32_16x16x32_bf16(A.s, bf, acc[nt], 0, 0, 0);
        }
    }

    float part[4];
    #pragma unroll
    for (int reg = 0; reg < 4; ++reg) {
        float sum = 0.f;
        #pragma unroll
        for (int nt = 0; nt < 4; ++nt) {
            int j = nt * 16 + n;
            sum = fmaf(fmaxf(acc[nt][reg] + b2[j], 0.f), W3[j], sum);
        }
        part[reg] = sum;
    }
    #pragma unroll
    for (int m = 1; m < 16; m <<= 1) {
        #pragma unroll
        for (int reg = 0; reg < 4; ++reg)
            part[reg] += __shfl_xor(part[reg], m, 64);
    }
    if (n == 0) {
        const float base3 = b3[0];
        #pragma unroll
        for (int reg = 0; reg < 4; ++reg) {
            int gid = tile * 16 + q * 4 + reg;
            int bb  = gid / NITEM;
            int it  = gid - bb * NITEM;
            float val = part[reg] + base3;
            if (it == 0) out[bb] = val;
            else         out[BATCH + bb * 64 + (it - 1)] = val;
        }
    }
}

// ======================= fused cooperative kernel ===========================
__global__ __launch_bounds__(256, 2) void fused(
    const float* __restrict__ embed, const float* __restrict__ W1,
    const float* __restrict__ b1, const float* __restrict__ W2,
    const float* __restrict__ b2, const float* __restrict__ W3,
    const float* __restrict__ b3, const int* __restrict__ h,
    const int* __restrict__ t, const int* __restrict__ ns,
    float* __restrict__ ws, float* __restrict__ out)
{
    cg::grid_group grid = cg::this_grid();
    __shared__ short8 ldsA[16 * LP];
    const int blk = blockIdx.x, tid = threadIdx.x;

    pack_w_body(blk, tid, W1, W2, ws);
    grid.sync();

    if (blk < 253) layer1_body(blk, tid, ldsA, embed, b1, t, ws);
    grid.sync();

    const int lane = tid & 63, wv = tid >> 6;
    for (int job = blk; job < 2080; job += GRID)
        score_tile(job * 4 + wv, lane, ws, b2, W3, b3, h, ns, out);
}

// ========================= standalone fallbacks =============================
__global__ __launch_bounds__(256) void pack_w_k(
    const float* __restrict__ W1, const float* __restrict__ W2,
    float* __restrict__ ws)
{
    pack_w_body(blockIdx.x, threadIdx.x, W1, W2, ws);
}

__global__ __launch_bounds__(256) void layer1_k(
    const float* __restrict__ embed, const float* __restrict__ b1,
    const int* __restrict__ t, float* __restrict__ ws)
{
    __shared__ short8 ldsA[16 * LP];
    layer1_body(blockIdx.x, threadIdx.x, ldsA, embed, b1, t, ws);
}

__global__ __launch_bounds__(256) void score_k(
    const float* __restrict__ ws,
    const float* __restrict__ b2, const float* __restrict__ W3,
    const float* __restrict__ b3,
    const int* __restrict__ h, const int* __restrict__ ns,
    float* __restrict__ out)
{
    score_tile(blockIdx.x * 4 + (threadIdx.x >> 6), threadIdx.x & 63,
               ws, b2, W3, b3, h, ns, out);
}

extern "C" void kernel_launch(void* const* d_in, const int* in_sizes, int n_in,
                              void* d_out, int out_size, void* d_ws, size_t ws_size,
                              hipStream_t stream) {
    const float* embed = (const float*)d_in[0];
    const float* W1    = (const float*)d_in[1];
    const float* b1    = (const float*)d_in[2];
    const float* W2    = (const float*)d_in[3];
    const float* b2    = (const float*)d_in[4];
    const float* W3    = (const float*)d_in[5];
    const float* b3    = (const float*)d_in[6];
    const int*   h     = (const int*)d_in[7];
    const int*   t     = (const int*)d_in[8];
    const int*   ns    = (const int*)d_in[9];
    float* out = (float*)d_out;
    float* ws  = (float*)d_ws;   // slab | W2f | W1f  (~3.4 MB)

    void* kargs[] = { (void*)&embed, (void*)&W1, (void*)&b1, (void*)&W2,
                      (void*)&b2, (void*)&W3, (void*)&b3, (void*)&h,
                      (void*)&t, (void*)&ns, (void*)&ws, (void*)&out };
    hipError_t err = hipLaunchCooperativeKernel((void*)fused, dim3(GRID),
                                                dim3(256), kargs, 0, stream);
    if (err != hipSuccess) {
        (void)hipGetLastError();   // clear sticky error, take proven 3-kernel path
        pack_w_k<<<65, 256, 0, stream>>>(W1, W2, ws);
        layer1_k<<<253, 256, 0, stream>>>(embed, b1, t, ws);
        score_k<<<(BATCH * NITEM) / 64, 256, 0, stream>>>(ws, b2, W3, b3,
                                                          h, ns, out);
    }
}

// Round 10
// 114.134 us; speedup vs baseline: 1.9661x; 1.9661x over previous
//
#include <hip/hip_runtime.h>

#define DIM    512
#define BATCH  2048
#define NDRUG  2000
#define H1     128
#define H2     64
#define NITEM  65        // 1 pos + 64 neg per sample
#define SLAB   774144    // floats: P 2000x128 | Q 2000x128 | Qt 2048x128
#define W2F_OFF  (SLAB)               // 16 KB  W2 bf16 B-fragments
#define W1F_OFF  (W2F_OFF + 4096)     // 256 KB W1 bf16 B-fragments
#define LP       65                   // layer1 LDS pitch in short8 (+1 pad)

typedef __attribute__((ext_vector_type(8))) short short8;
typedef __attribute__((ext_vector_type(4))) float floatx4;

// f32 -> bf16 RNE (bit trick; inputs finite)
__device__ inline unsigned f2bf(float x) {
    union { float f; unsigned u; } v; v.f = x;
    unsigned r = v.u + 0x7fffu + ((v.u >> 16) & 1u);
    return r >> 16;
}
__device__ inline unsigned pkbf(float a, float b) {
    return f2bf(a) | (f2bf(b) << 16);
}
__device__ inline short8 cvt8(const float* __restrict__ src) {
    float4 a = *(const float4*)src, b = *(const float4*)(src + 4);
    union { short8 s; unsigned u[4]; } v;
    v.u[0] = pkbf(a.x, a.y); v.u[1] = pkbf(a.z, a.w);
    v.u[2] = pkbf(b.x, b.y); v.u[3] = pkbf(b.z, b.w);
    return v.s;
}

// ---------------------------------------------------------------------------
// Kernel 1: weight packing. 65 blocks x 256.
// B-frag (mfma_f32_16x16x32_bf16): lane L holds
//   B[k = kt*32 + (L>>4)*8 + j][n = nt*16 + (L&15)], j=0..7.
// W1f storage index = (half*8 + nt)*16 + kt   (wave-contiguous kt-runs)
// W2f storage index = kt*4 + nt               (score reads it via LDS)
// ---------------------------------------------------------------------------
__global__ __launch_bounds__(256) void pack_w(
    const float* __restrict__ W1, const float* __restrict__ W2,
    float* __restrict__ ws)
{
    const int blk = blockIdx.x, tid = threadIdx.x;
    if (blk < 64) {
        short8* W1f = (short8*)(ws + W1F_OFF);
        int item = blk * 256 + tid;                // < 16384
        int frag = item >> 6, fl = item & 63;
        int half = frag >> 7, rem = frag & 127;
        int nt = rem >> 4, kt = rem & 15;
        int fn = fl & 15, fq = fl >> 4;
        short8 v;
        #pragma unroll
        for (int j = 0; j < 8; ++j) {
            int k = half * DIM + kt * 32 + fq * 8 + j;
            v[j] = (short)f2bf(W1[k * H1 + nt * 16 + fn]);
        }
        W1f[item] = v;
    } else {
        short8* W2f = (short8*)(ws + W2F_OFF);
        #pragma unroll
        for (int i = 0; i < 4; ++i) {
            int item = i * 256 + tid;              // < 1024
            int frag = item >> 6, fl = item & 63;
            int kt = frag >> 2, nt = frag & 3;
            int fn = fl & 15, fq = fl >> 4;
            short8 v;
            #pragma unroll
            for (int j = 0; j < 8; ++j)
                v[j] = (short)f2bf(W2[(kt * 32 + fq * 8 + j) * H2 + nt * 16 + fn]);
            W2f[item] = v;
        }
    }
}

// ---------------------------------------------------------------------------
// layer-1 MFMA core: NT column-tiles, K=512, double-buffered bulk B-loads
// (4-kt groups) so exposed global latency is ~4 rounds, overlapped with MFMA.
// Wh points at this wave's first fragment: (half*8 + ntbase)*16*64.
// Frag (i,kt) lives at Wh[(i*16 + kt)*64 + lane].
// ---------------------------------------------------------------------------
template<int NT>
__device__ inline void l1_core(const short8* __restrict__ Wh,
                               const short8* __restrict__ ldsA,
                               int n, int q, int lane, floatx4* acc)
{
    short8 B[2][NT * 4];
    #pragma unroll
    for (int i = 0; i < NT; ++i)
        #pragma unroll
        for (int k = 0; k < 4; ++k)
            B[0][i * 4 + k] = Wh[(i * 16 + k) * 64 + lane];

    #pragma unroll
    for (int g = 0; g < 4; ++g) {
        const int cur = g & 1, nxt = cur ^ 1;
        if (g < 3) {
            #pragma unroll
            for (int i = 0; i < NT; ++i)
                #pragma unroll
                for (int k = 0; k < 4; ++k)
                    B[nxt][i * 4 + k] = Wh[(i * 16 + (g + 1) * 4 + k) * 64 + lane];
        }
        #pragma unroll
        for (int k = 0; k < 4; ++k) {
            short8 a = ldsA[n * LP + (g * 4 + k) * 4 + q];
            #pragma unroll
            for (int i = 0; i < NT; ++i)
                acc[i] = __builtin_amdgcn_mfma_f32_16x16x32_bf16(
                             a, B[cur][i * 4 + k], acc[i], 0, 0, 0);
        }
    }
}

// ---------------------------------------------------------------------------
// Kernel 2: layer-1. 253 blocks x 256. embed staged f32->bf16 into LDS in
// A-frag order. blk<125: 16 drug rows, waves cover P nt0-7 / Q nt0-7
// (4 tiles each). blk>=125: 16 t-gathered rows, waves cover Qt nt0-7
// (2 tiles each). b1 folded into tail tables (Q, Qt).
// ---------------------------------------------------------------------------
__global__ __launch_bounds__(256) void layer1_k(
    const float* __restrict__ embed, const float* __restrict__ b1,
    const int* __restrict__ t, float* __restrict__ ws)
{
    __shared__ short8 ldsA[16 * LP];              // 16.6 KB
    const short8* W1f = (const short8*)(ws + W1F_OFF);
    const int blk = blockIdx.x, tid = threadIdx.x;
    const bool isPQ = blk < 125;
    const int rowbase = isPQ ? blk * 16 : (blk - 125) * 16;
    const int lane = tid & 63, wv = tid >> 6;
    const int n = lane & 15, q = lane >> 4;

    #pragma unroll
    for (int i = 0; i < 4; ++i) {
        int u = i * 256 + tid;
        int r = u >> 6, c = u & 63;
        size_t grow = isPQ ? (size_t)(rowbase + r) : (size_t)t[rowbase + r];
        ldsA[r * LP + c] = cvt8(embed + grow * DIM + c * 8);
    }
    __syncthreads();

    if (isPQ) {
        const int T0 = wv * 4;
        const int half = (T0 >= 8) ? 1 : 0;        // 0 -> P, 1 -> Q
        const int ntbase = T0 & 7;
        floatx4 acc[4];
        #pragma unroll
        for (int i = 0; i < 4; ++i) acc[i] = (floatx4){0.f, 0.f, 0.f, 0.f};
        const short8* Wh = W1f + (size_t)((half * 8 + ntbase) * 16) * 64;
        l1_core<4>(Wh, ldsA, n, q, lane, acc);
        float* tbl = ws + (half ? NDRUG * H1 : 0);
        #pragma unroll
        for (int i = 0; i < 4; ++i) {
            int nt = ntbase + i;
            float badd = half ? b1[nt * 16 + n] : 0.f;
            #pragma unroll
            for (int reg = 0; reg < 4; ++reg)
                tbl[(size_t)(rowbase + q * 4 + reg) * H1 + nt * 16 + n] =
                    acc[i][reg] + badd;
        }
    } else {
        const int ntbase = wv * 2;                 // Qt, half 1
        floatx4 acc[2];
        #pragma unroll
        for (int i = 0; i < 2; ++i) acc[i] = (floatx4){0.f, 0.f, 0.f, 0.f};
        const short8* Wh = W1f + (size_t)((8 + ntbase) * 16) * 64;
        l1_core<2>(Wh, ldsA, n, q, lane, acc);
        float* tbl = ws + 2 * (NDRUG * H1);
        #pragma unroll
        for (int i = 0; i < 2; ++i) {
            int nt = ntbase + i;
            float badd = b1[nt * 16 + n];
            #pragma unroll
            for (int reg = 0; reg < 4; ++reg)
                tbl[(size_t)(rowbase + q * 4 + reg) * H1 + nt * 16 + n] =
                    acc[i][reg] + badd;
        }
    }
}

// ---------------------------------------------------------------------------
// Kernel 3: score. 2080 blocks x 256 (1 tile/wave, 8 waves/SIMD TLP).
// W2f staged into LDS per block; sample indices loaded BEFORE the staging
// barrier (latency overlap); all 16 P/Q row float4s bulk-loaded into regs
// in one round; MFMA B-operands from LDS. Epilogue relu+W3 + 16-lane
// shuffle reduce (unchanged numerics).
// ---------------------------------------------------------------------------
__global__ __launch_bounds__(256) void score_k(
    const float* __restrict__ ws,
    const float* __restrict__ b2, const float* __restrict__ W3,
    const float* __restrict__ b3,
    const int* __restrict__ h, const int* __restrict__ ns,
    float* __restrict__ out)
{
    __shared__ short8 w2lds[1024];                // 16 KB
    const float* P  = ws;
    const float* Q  = ws + NDRUG * H1;
    const float* Qt = Q + NDRUG * H1;
    const short8* W2f = (const short8*)(ws + W2F_OFF);

    const int tid = threadIdx.x;
    const int lane = tid & 63, wv = tid >> 6;
    const int tile = blockIdx.x * 4 + wv;          // 0..8319
    const int n = lane & 15, q = lane >> 4;

    // Index loads issued before the staging barrier — latency overlaps.
    const int sg   = tile * 16 + n;
    const int b    = sg / NITEM;
    const int item = sg - b * NITEM;
    const bool midQ = (item >= 1 && item <= 32);
    const int rowA = (item <= 32) ? h[b] : ns[b * 64 + 32 + (item - 33)];
    const int rowB = midQ ? ns[b * 64 + item - 1] : b;

    // Stage W2f into LDS (coalesced, 4 short8 per thread).
    #pragma unroll
    for (int i = 0; i < 4; ++i)
        w2lds[i * 256 + tid] = W2f[i * 256 + tid];
    __syncthreads();

    const float* Pr = P + (size_t)rowA * H1;
    const float* Qr = (midQ ? Q : Qt) + (size_t)rowB * H1;

    // Bulk-load all 16 row float4s -> one exposed latency round.
    float4 pr[8], qr[8];
    #pragma unroll
    for (int kt = 0; kt < 4; ++kt) {
        const int kb = kt * 32 + q * 8;
        pr[kt * 2]     = *(const float4*)(Pr + kb);
        pr[kt * 2 + 1] = *(const float4*)(Pr + kb + 4);
        qr[kt * 2]     = *(const float4*)(Qr + kb);
        qr[kt * 2 + 1] = *(const float4*)(Qr + kb + 4);
    }

    floatx4 acc[4];
    #pragma unroll
    for (int nt = 0; nt < 4; ++nt) acc[nt] = (floatx4){0.f, 0.f, 0.f, 0.f};

    #pragma unroll
    for (int kt = 0; kt < 4; ++kt) {
        float4 p0 = pr[kt * 2], p1 = pr[kt * 2 + 1];
        float4 q0 = qr[kt * 2], q1 = qr[kt * 2 + 1];
        union { short8 s; unsigned u[4]; } A;
        A.u[0] = pkbf(fmaxf(p0.x + q0.x, 0.f), fmaxf(p0.y + q0.y, 0.f));
        A.u[1] = pkbf(fmaxf(p0.z + q0.z, 0.f), fmaxf(p0.w + q0.w, 0.f));
        A.u[2] = pkbf(fmaxf(p1.x + q1.x, 0.f), fmaxf(p1.y + q1.y, 0.f));
        A.u[3] = pkbf(fmaxf(p1.z + q1.z, 0.f), fmaxf(p1.w + q1.w, 0.f));
        #pragma unroll
        for (int nt = 0; nt < 4; ++nt) {
            short8 bf = w2lds[(kt * 4 + nt) * 64 + lane];
            acc[nt] = __builtin_amdgcn_mfma_f32_16x16x32_bf16(A.s, bf, acc[nt], 0, 0, 0);
        }
    }

    float part[4];
    #pragma unroll
    for (int reg = 0; reg < 4; ++reg) {
        float sum = 0.f;
        #pragma unroll
        for (int nt = 0; nt < 4; ++nt) {
            int j = nt * 16 + n;
            sum = fmaf(fmaxf(acc[nt][reg] + b2[j], 0.f), W3[j], sum);
        }
        part[reg] = sum;
    }
    #pragma unroll
    for (int m = 1; m < 16; m <<= 1) {
        #pragma unroll
        for (int reg = 0; reg < 4; ++reg)
            part[reg] += __shfl_xor(part[reg], m, 64);
    }
    if (n == 0) {
        const float base3 = b3[0];
        #pragma unroll
        for (int reg = 0; reg < 4; ++reg) {
            int gid = tile * 16 + q * 4 + reg;
            int bb  = gid / NITEM;
            int it  = gid - bb * NITEM;
            float val = part[reg] + base3;
            if (it == 0) out[bb] = val;
            else         out[BATCH + bb * 64 + (it - 1)] = val;
        }
    }
}

extern "C" void kernel_launch(void* const* d_in, const int* in_sizes, int n_in,
                              void* d_out, int out_size, void* d_ws, size_t ws_size,
                              hipStream_t stream) {
    const float* embed = (const float*)d_in[0];
    const float* W1    = (const float*)d_in[1];
    const float* b1    = (const float*)d_in[2];
    const float* W2    = (const float*)d_in[3];
    const float* b2    = (const float*)d_in[4];
    const float* W3    = (const float*)d_in[5];
    const float* b3    = (const float*)d_in[6];
    const int*   h     = (const int*)d_in[7];
    const int*   t     = (const int*)d_in[8];
    const int*   ns    = (const int*)d_in[9];
    float* out = (float*)d_out;
    float* ws  = (float*)d_ws;   // slab | W2f | W1f  (~3.4 MB)

    pack_w<<<65, 256, 0, stream>>>(W1, W2, ws);
    layer1_k<<<253, 256, 0, stream>>>(embed, b1, t, ws);
    score_k<<<(BATCH * NITEM) / 64, 256, 0, stream>>>(ws, b2, W3, b3,
                                                      h, ns, out);
}